// Round 1
// baseline (126.946 us; speedup 1.0000x reference)
//
#include <hip/hip_runtime.h>

typedef float vf4 __attribute__((ext_vector_type(4)));

#define MASKV (-1000000.0f)
#define LOG2E 1.4426950408889634f
#define TWO_LOG2E 2.8853900817779268f

__device__ __forceinline__ float fexp2(float x) {
#if __has_builtin(__builtin_amdgcn_exp2f)
  return __builtin_amdgcn_exp2f(x);
#else
  return exp2f(x);
#endif
}
__device__ __forceinline__ float frcp(float x) {
#if __has_builtin(__builtin_amdgcn_rcpf)
  return __builtin_amdgcn_rcpf(x);
#else
  return 1.0f / x;
#endif
}

// ---------------------------------------------------------------------------
// Kernel 1: projections. C(4096x256): rows 0..2047 = queries@Wq^T -> Qp,
// rows 2048..4095 = keyes@Wk^T -> Kp. Result pre-scaled by 2*log2(e) so the
// scores kernel can feed exp2 directly (tanh(x) = 1 - 2/(exp2(2x*log2e)+1)).
// 64x64 tile / block of 256, 4x4 outputs per thread, K chunks of 16.
__global__ __launch_bounds__(256) void proj_kernel(
    const float* __restrict__ queries, const float* __restrict__ keyes,
    const float* __restrict__ Wq, const float* __restrict__ Wk,
    float* __restrict__ Qp, float* __restrict__ Kp) {
  __shared__ alignas(16) float At[16 * 68];  // [k][m], pad 68 (272B = 16*17 aligned)
  __shared__ alignas(16) float Bt[16 * 68];  // [k][n]
  const int t = threadIdx.x;
  const int m0 = blockIdx.x * 64;
  const int n0 = blockIdx.y * 64;
  const bool isQ = (m0 < 2048);
  const float* X = isQ ? queries : keyes;
  const float* W = isQ ? Wq : Wk;
  float* C = isQ ? Qp : Kp;
  const int mb = isQ ? m0 : (m0 - 2048);

  const int lm = t >> 2;           // 0..63 row
  const int lq = t & 3;            // 0..3 float4 within 16-wide chunk
  const int mm4 = (t & 15) * 4;
  const int nn4 = (t >> 4) * 4;

  float acc[4][4] = {};
  for (int kc = 0; kc < 256; kc += 16) {
    __syncthreads();
    vf4 xa = *(const vf4*)&X[(mb + lm) * 256 + kc + lq * 4];
    vf4 wb = *(const vf4*)&W[(n0 + lm) * 256 + kc + lq * 4];
#pragma unroll
    for (int c = 0; c < 4; ++c) {
      At[(lq * 4 + c) * 68 + lm] = xa[c];
      Bt[(lq * 4 + c) * 68 + lm] = wb[c];
    }
    __syncthreads();
#pragma unroll
    for (int kk = 0; kk < 16; ++kk) {
      vf4 a4 = *(const vf4*)&At[kk * 68 + mm4];
      vf4 b4 = *(const vf4*)&Bt[kk * 68 + nn4];
#pragma unroll
      for (int i = 0; i < 4; ++i)
#pragma unroll
        for (int j = 0; j < 4; ++j) acc[i][j] += a4[i] * b4[j];
    }
  }
#pragma unroll
  for (int i = 0; i < 4; ++i) {
    vf4 o = {acc[i][0] * TWO_LOG2E, acc[i][1] * TWO_LOG2E,
             acc[i][2] * TWO_LOG2E, acc[i][3] * TWO_LOG2E};
    *(vf4*)&C[(mb + mm4 + i) * 256 + n0 + nn4] = o;
  }
}

// ---------------------------------------------------------------------------
// Kernel 2 (dominant): ST[b][j][i] = sum_h tanh-score, masked.
// score = Swv - 2 * sum_h wv[h] / (exp2(q'+k') + 1),  q',k' pre-scaled.
// Block: 32x32 (i,j) tile, 256 threads, 2x2 scores/thread, h chunks of 32.
__global__ __launch_bounds__(256) void scores_kernel(
    const float* __restrict__ Qp, const float* __restrict__ Kp,
    const float* __restrict__ Wv, const int* __restrict__ valid_lens,
    float* __restrict__ ST) {
  __shared__ alignas(16) float Qc[32 * 36];  // pad 36 (144B = 16*9 aligned)
  __shared__ alignas(16) float Kc[32 * 36];
  __shared__ alignas(16) float wvs[256];
  const int t = threadIdx.x;
  const int b = blockIdx.z;
  const int i0 = blockIdx.x * 32;
  const int j0 = blockIdx.y * 32;

  if (t < 64) *(vf4*)&wvs[t * 4] = *(const vf4*)&Wv[t * 4];
  __syncthreads();

  float Swv;  // sum_h wv[h], uniform across block
  {
    vf4 w4 = *(const vf4*)&wvs[(t & 63) * 4];
    float sw = w4[0] + w4[1] + w4[2] + w4[3];
#pragma unroll
    for (int off = 1; off < 64; off <<= 1) sw += __shfl_xor(sw, off, 64);
    Swv = sw;
  }

  const int lr = t >> 3, lq = t & 7;  // load mapping: 32 rows x 8 float4
  const int ti = t & 15, tj = t >> 4; // compute mapping
  float acc[2][2] = {};

  for (int hc = 0; hc < 8; ++hc) {
    __syncthreads();
    vf4 qv = *(const vf4*)&Qp[((b << 8) + i0 + lr) * 256 + hc * 32 + lq * 4];
    vf4 kv = *(const vf4*)&Kp[((b << 8) + j0 + lr) * 256 + hc * 32 + lq * 4];
    *(vf4*)&Qc[lr * 36 + lq * 4] = qv;
    *(vf4*)&Kc[lr * 36 + lq * 4] = kv;
    __syncthreads();
#pragma unroll
    for (int hh = 0; hh < 8; ++hh) {
      vf4 q0 = *(const vf4*)&Qc[ti * 36 + hh * 4];
      vf4 q1 = *(const vf4*)&Qc[(ti + 16) * 36 + hh * 4];
      vf4 k0 = *(const vf4*)&Kc[tj * 36 + hh * 4];
      vf4 k1 = *(const vf4*)&Kc[(tj + 16) * 36 + hh * 4];
      vf4 wv4 = *(const vf4*)&wvs[hc * 32 + hh * 4];
#pragma unroll
      for (int c = 0; c < 4; ++c) {
        acc[0][0] += wv4[c] * frcp(fexp2(q0[c] + k0[c]) + 1.0f);
        acc[0][1] += wv4[c] * frcp(fexp2(q0[c] + k1[c]) + 1.0f);
        acc[1][0] += wv4[c] * frcp(fexp2(q1[c] + k0[c]) + 1.0f);
        acc[1][1] += wv4[c] * frcp(fexp2(q1[c] + k1[c]) + 1.0f);
      }
    }
  }
  const int len = valid_lens[b];
#pragma unroll
  for (int jq = 0; jq < 2; ++jq) {
    const int jg = j0 + tj + jq * 16;
    const bool masked = (jg >= len);
#pragma unroll
    for (int iq = 0; iq < 2; ++iq) {
      const int ig = i0 + ti + iq * 16;
      float s = masked ? MASKV : (Swv - 2.0f * acc[iq][jq]);
      ST[(((b << 8) + jg) << 8) + ig] = s;
    }
  }
}

// ---------------------------------------------------------------------------
// Kernel 3: softmax over i (reference axis=1) = contiguous rows of ST[b][j][:].
// One wave per row, 4 elements/lane, shuffle reductions, in-place.
__global__ __launch_bounds__(256) void softmax_kernel(float* __restrict__ ST) {
  const int t = threadIdx.x;
  const int l = t & 63;
  const int row = blockIdx.x * 4 + (t >> 6);
  vf4* rp = (vf4*)(ST + row * 256);
  vf4 v = rp[l];
  float mx = fmaxf(fmaxf(v[0], v[1]), fmaxf(v[2], v[3]));
#pragma unroll
  for (int off = 1; off < 64; off <<= 1) mx = fmaxf(mx, __shfl_xor(mx, off, 64));
  vf4 e;
#pragma unroll
  for (int c = 0; c < 4; ++c) e[c] = fexp2((v[c] - mx) * LOG2E);
  float s = e[0] + e[1] + e[2] + e[3];
#pragma unroll
  for (int off = 1; off < 64; off <<= 1) s += __shfl_xor(s, off, 64);
  const float r = frcp(s);
#pragma unroll
  for (int c = 0; c < 4; ++c) e[c] *= r;
  rp[l] = e;
}

// ---------------------------------------------------------------------------
// Kernel 4: out[b,i,d] = sum_j WT[b][j][i] * V[b][j][d]. 32x32 tile / block,
// 4 outputs per thread (1 row x float4), j chunks of 32.
__global__ __launch_bounds__(256) void out_kernel(
    const float* __restrict__ WT, const float* __restrict__ V,
    float* __restrict__ out) {
  __shared__ alignas(16) float Ws[32 * 36];
  __shared__ alignas(16) float Vs[32 * 36];
  const int t = threadIdx.x;
  const int b = blockIdx.z;
  const int i0 = blockIdx.x * 32;
  const int d0 = blockIdx.y * 32;
  const int jj = t >> 3, lq = t & 7;
  const int ii = t >> 3, dd = (t & 7) * 4;
  vf4 acc = {0.f, 0.f, 0.f, 0.f};
  for (int jc = 0; jc < 8; ++jc) {
    __syncthreads();
    const int jg = jc * 32 + jj;
    *(vf4*)&Ws[jj * 36 + lq * 4] = *(const vf4*)&WT[((b << 8) + jg) * 256 + i0 + lq * 4];
    *(vf4*)&Vs[jj * 36 + lq * 4] = *(const vf4*)&V[((b << 8) + jg) * 256 + d0 + lq * 4];
    __syncthreads();
#pragma unroll
    for (int j2 = 0; j2 < 32; ++j2) {
      const float w = Ws[j2 * 36 + ii];
      vf4 v4 = *(const vf4*)&Vs[j2 * 36 + dd];
      acc += w * v4;
    }
  }
  *(vf4*)&out[((b << 8) + i0 + ii) * 256 + d0 + dd] = acc;
}

// ---------------------------------------------------------------------------
extern "C" void kernel_launch(void* const* d_in, const int* in_sizes, int n_in,
                              void* d_out, int out_size, void* d_ws, size_t ws_size,
                              hipStream_t stream) {
  const float* queries = (const float*)d_in[0];
  const float* keyes = (const float*)d_in[1];
  const float* values = (const float*)d_in[2];
  const int* valid_lens = (const int*)d_in[3];
  const float* Wq = (const float*)d_in[4];
  const float* Wk = (const float*)d_in[5];
  const float* Wv = (const float*)d_in[6];
  float* out = (float*)d_out;

  float* Qp = (float*)d_ws;        // 8*256*256 = 524288 floats (2 MB)
  float* Kp = Qp + 524288;         // 2 MB
  float* ST = Kp + 524288;         // 2 MB, layout [b][j][i]

  proj_kernel<<<dim3(64, 4, 1), 256, 0, stream>>>(queries, keyes, Wq, Wk, Qp, Kp);
  scores_kernel<<<dim3(8, 8, 8), 256, 0, stream>>>(Qp, Kp, Wv, valid_lens, ST);
  softmax_kernel<<<512, 256, 0, stream>>>(ST);
  out_kernel<<<dim3(8, 8, 8), 256, 0, stream>>>(ST, values, out);
}